// Round 9
// baseline (165.765 us; speedup 1.0000x reference)
//
#include <hip/hip_runtime.h>
#include <hip/hip_bf16.h>
#include <math.h>

#define DIM 1024
#define HID 2048
#define NEXP 8
#define NTOK 1024   // B*T
#define TOPK 2

typedef __attribute__((ext_vector_type(4))) float f32x4;
typedef __attribute__((ext_vector_type(8))) short bf16x8;
typedef __attribute__((ext_vector_type(4))) short bf16x4;

__device__ inline short bf1(float f) {
    union { __hip_bfloat16 b; short s; } u; u.b = __float2bfloat16(f); return u.s;
}
__device__ inline bf16x4 cvt4(f32x4 v) {
    bf16x4 r;
#pragma unroll
    for (int i = 0; i < 4; ++i) r[i] = bf1(v[i]);
    return r;
}
__device__ inline bf16x8 cat8(bf16x4 lo, bf16x4 hi) {
    bf16x8 r;
#pragma unroll
    for (int i = 0; i < 4; ++i) { r[i] = lo[i]; r[i + 4] = hi[i]; }
    return r;
}

// async global->LDS: LDS dest = wave-uniform base + lane*16; global src per-lane.
__device__ __forceinline__ void gload16(const void* g, void* l) {
    __builtin_amdgcn_global_load_lds(
        (const __attribute__((address_space(1))) void*)g,
        (__attribute__((address_space(3))) void*)l,
        16, 0, 0);
}

// ---------------- router (fused with x->bf16 convert) ----------------
__global__ __launch_bounds__(64) void router_kernel(
    const float* __restrict__ x, const float* __restrict__ rw,
    __hip_bfloat16* __restrict__ xb,
    int* __restrict__ counts, int* __restrict__ slot_list, float* __restrict__ w_list)
{
    int t = blockIdx.x;
    int lane = threadIdx.x;
    const float* xr = x + (size_t)t * DIM;
    f32x4 xv[4];
#pragma unroll
    for (int qq = 0; qq < 4; ++qq) xv[qq] = *(const f32x4*)(xr + qq * 256 + lane * 4);
#pragma unroll
    for (int qq = 0; qq < 4; ++qq)
        *(bf16x4*)(xb + (size_t)t * DIM + qq * 256 + lane * 4) = cvt4(xv[qq]);

    float acc[NEXP];
#pragma unroll
    for (int e = 0; e < NEXP; ++e) {
        const float* rwe = rw + e * DIM;
        f32x4 s4 = (f32x4)(0.f);
#pragma unroll
        for (int qq = 0; qq < 4; ++qq) {
            f32x4 wv = *(const f32x4*)(rwe + qq * 256 + lane * 4);
            s4 += xv[qq] * wv;
        }
        acc[e] = s4[0] + s4[1] + s4[2] + s4[3];
    }
#pragma unroll
    for (int off = 32; off > 0; off >>= 1) {
#pragma unroll
        for (int e = 0; e < NEXP; ++e) acc[e] += __shfl_down(acc[e], off, 64);
    }
    if (lane == 0) {
        int i1 = 0;
#pragma unroll
        for (int e = 1; e < NEXP; ++e) if (acc[e] > acc[i1]) i1 = e;
        int i2 = -1;
#pragma unroll
        for (int e = 0; e < NEXP; ++e) {
            if (e == i1) continue;
            if (i2 < 0 || acc[e] > acc[i2]) i2 = e;
        }
        float w1 = 1.f / (1.f + expf(acc[i2] - acc[i1]));   // softmax renorm over top-2
        float w2 = 1.f - w1;
        int p1 = atomicAdd(&counts[i1], 1);
        slot_list[i1 * NTOK + p1] = t * 2 + 0;
        w_list[i1 * NTOK + p1] = w1;
        int p2 = atomicAdd(&counts[i2], 1);
        slot_list[i2 * NTOK + p2] = t * 2 + 1;
        w_list[i2 * NTOK + p2] = w2;
    }
}

// ---------------- gate+up: deep-pipelined grouped MFMA GEMM ----------------
// Tile: M=128 tokens x strip of 32 h-cols (G and U), BK=32. 4-deep LDS buffers
// (16KB each: X bf16 8KB + B f32 8KB), all staging via global_load_lds,
// 3-step prefetch lead, counted vmcnt(8) (= 2 future steps x 4 gloads/wave).
// Waves (wm,wn): wm = M-half(64), wn = col-half(16). 8 MFMA/step/wave.
// grid 1024: bid=(s&7)+8*(z+2*(s>>3)), s=e*64+strip in [0,512), z in {0,1}
// (z-replicas share bid%8 -> same XCD -> weight panel L2-dedupe).
__global__ __launch_bounds__(256) void gateup_mfma(
    const __hip_bfloat16* __restrict__ xb, const float* __restrict__ wg,
    const float* __restrict__ wu, const int* __restrict__ counts,
    const int* __restrict__ slot_list, const float* __restrict__ w_list,
    const __hip_bfloat16* __restrict__ zrow, __hip_bfloat16* __restrict__ h_buf)
{
    __shared__ f32x4 ldsv[4][1024];   // 4 x 16KB

    int bid = blockIdx.x;
    int pl = bid & 7, sf = bid >> 3;
    int z = sf & 1;
    int s = ((sf >> 1) << 3) | pl;        // 0..511
    int e = s >> 6, strip = s & 63;
    int hb = strip * 32;

    int n_e = counts[e];
    const int* sl = slot_list + e * NTOK;
    const float* wl = w_list + e * NTOK;
    const float* WG = wg + (size_t)e * HID * DIM;
    const float* WU = wu + (size_t)e * HID * DIM;

    int tid = threadIdx.x, lane = tid & 63, wv = tid >> 6;
    int fr = lane & 15, fq = lane >> 4;
    int wm = wv >> 1, wn = wv & 1;

    // staging lane decode: X regions 16 rows x 4 chunks; B regions 8 rows x 8 chunks
    int xr = lane >> 2, cX = lane & 3;
    int br = lane >> 3, cB = lane & 7;

    // B regions (per wave: 2wv, 2wv+1): tile rows 0-31 = G strip, 32-63 = U strip
    int rb0 = 2 * wv, rb1 = 2 * wv + 1;
    const float* bb0 = (rb0 < 4) ? (WG + (size_t)(hb + rb0 * 8 + br) * DIM)
                                 : (WU + (size_t)(hb + (rb0 - 4) * 8 + br) * DIM);
    const float* bb1 = (rb1 < 4) ? (WG + (size_t)(hb + rb1 * 8 + br) * DIM)
                                 : (WU + (size_t)(hb + (rb1 - 4) * 8 + br) * DIM);
    const char* pb0 = (const char*)bb0 + (cB ^ br) * 16;   // src swizzle: slot s holds chunk s^row
    const char* pb1 = (const char*)bb1 + (cB ^ br) * 16;
    int sxg = ((cX - (xr >> 1)) & 3) * 16;                 // X src swizzle: slot s holds chunk (s-(row>>1))&3

    char* b0 = (char*)&ldsv[0][0];

    for (int m0 = z * 128; m0 < n_e; m0 += 256) {
        int rows = n_e - m0; if (rows > 128) rows = 128;
        int r0 = 2 * wv * 16 + xr, r1 = r0 + 16;
        const char* px0 = (const char*)((r0 < rows) ? (xb + (size_t)(sl[m0 + r0] >> 1) * DIM) : zrow) + sxg;
        const char* px1 = (const char*)((r1 < rows) ? (xb + (size_t)(sl[m0 + r1] >> 1) * DIM) : zrow) + sxg;

        f32x4 accg[4], accu[4];
#pragma unroll
        for (int ms = 0; ms < 4; ++ms) { accg[ms] = (f32x4)(0.f); accu[ms] = (f32x4)(0.f); }

        // prologue: stage tiles 0..2
#pragma unroll
        for (int st = 0; st < 3; ++st) {
            char* dX = b0 + st * 16384 + (2 * wv) * 1024;
            gload16(px0 + st * 64, dX);
            gload16(px1 + st * 64, dX + 1024);
            char* dB = b0 + st * 16384 + 8192 + (2 * wv) * 1024;
            gload16(pb0 + st * 128, dB);
            gload16(pb1 + st * 128, dB + 1024);
        }

#pragma unroll 1
        for (int t = 0; t < 32; ++t) {
            if (t < 30)       asm volatile("s_waitcnt vmcnt(8)" ::: "memory");
            else if (t == 30) asm volatile("s_waitcnt vmcnt(4)" ::: "memory");
            else              asm volatile("s_waitcnt vmcnt(0)" ::: "memory");
            __builtin_amdgcn_s_barrier();

            const char* Xb = b0 + (t & 3) * 16384;
            const char* Bb = Xb + 8192;
            bf16x8 af[4];
#pragma unroll
            for (int ms = 0; ms < 4; ++ms) {
                int row = wm * 64 + ms * 16 + fr;
                int slot = (fq + (row >> 1)) & 3;
                af[ms] = *(const bf16x8*)(Xb + row * 64 + slot * 16);
            }
            int rg = wn * 16 + fr;
            f32x4 ga = *(const f32x4*)(Bb + rg * 128 + ((2 * fq) ^ (fr & 7)) * 16);
            f32x4 gb = *(const f32x4*)(Bb + rg * 128 + ((2 * fq + 1) ^ (fr & 7)) * 16);
            bf16x8 bgf = cat8(cvt4(ga), cvt4(gb));
            int ru = 32 + wn * 16 + fr;
            f32x4 ua = *(const f32x4*)(Bb + ru * 128 + ((2 * fq) ^ (fr & 7)) * 16);
            f32x4 ub = *(const f32x4*)(Bb + ru * 128 + ((2 * fq + 1) ^ (fr & 7)) * 16);
            bf16x8 buf_ = cat8(cvt4(ua), cvt4(ub));
#pragma unroll
            for (int ms = 0; ms < 4; ++ms) {
                accg[ms] = __builtin_amdgcn_mfma_f32_16x16x32_bf16(af[ms], bgf, accg[ms], 0, 0, 0);
                accu[ms] = __builtin_amdgcn_mfma_f32_16x16x32_bf16(af[ms], buf_, accu[ms], 0, 0, 0);
            }
            __builtin_amdgcn_s_barrier();   // all waves done reading buf[t&3]

            if (t < 29) {                   // issue tile t+3 into buf[(t+3)&3]
                int kt = t + 3, kb = kt & 3;
                char* dX = b0 + kb * 16384 + (2 * wv) * 1024;
                gload16(px0 + kt * 64, dX);
                gload16(px1 + kt * 64, dX + 1024);
                char* dB = b0 + kb * 16384 + 8192 + (2 * wv) * 1024;
                gload16(pb0 + kt * 128, dB);
                gload16(pb1 + kt * 128, dB + 1024);
            }
        }

        // epilogue: h = w * silu(g) * u -> bf16; col = hb + wn*16 + fr
#pragma unroll
        for (int ms = 0; ms < 4; ++ms) {
#pragma unroll
            for (int reg = 0; reg < 4; ++reg) {
                int r = wm * 64 + ms * 16 + fq * 4 + reg;
                if (r < rows) {
                    int slot = sl[m0 + r];
                    float w = wl[m0 + r];
                    float g = accg[ms][reg], u = accu[ms][reg];
                    float h = w * (g / (1.f + expf(-g))) * u;
                    h_buf[(size_t)slot * HID + hb + wn * 16 + fr] = __float2bfloat16(h);
                }
            }
        }
    }
}

// ---------------- down: same deep-pipelined structure ----------------
// Tile: M=128 slots x 32 d-cols, BK=32. Buffers 12KB (H 8KB + W 4KB) x4 = 48KB.
// Per wave per step: 2 H-gloads + 1 W-gload -> counted vmcnt(6).
// grid 512: s = e*32+strip in [0,256), z in {0,1}.
__global__ __launch_bounds__(256) void down_mfma(
    const __hip_bfloat16* __restrict__ h_buf, const float* __restrict__ wd,
    const int* __restrict__ counts, const int* __restrict__ slot_list,
    const __hip_bfloat16* __restrict__ zrow, float* __restrict__ ybuf)
{
    __shared__ f32x4 ldsv[4][768];    // 4 x 12KB

    int bid = blockIdx.x;
    int pl = bid & 7, sf = bid >> 3;
    int z = sf & 1;
    int s = ((sf >> 1) << 3) | pl;        // 0..255
    int e = s >> 5, strip = s & 31;
    int db = strip * 32;

    int n_e = counts[e];
    const int* sl = slot_list + e * NTOK;
    const float* WD = wd + (size_t)e * DIM * HID;

    int tid = threadIdx.x, lane = tid & 63, wv = tid >> 6;
    int fr = lane & 15, fq = lane >> 4;
    int wm = wv >> 1, wn = wv & 1;

    int xr = lane >> 2, cX = lane & 3;
    int br = lane >> 3, cB = lane & 7;

    const char* pb = (const char*)(WD + (size_t)(db + wv * 8 + br) * HID) + (cB ^ br) * 16;
    int sxg = ((cX - (xr >> 1)) & 3) * 16;

    char* b0 = (char*)&ldsv[0][0];

    for (int m0 = z * 128; m0 < n_e; m0 += 256) {
        int rows = n_e - m0; if (rows > 128) rows = 128;
        int r0 = 2 * wv * 16 + xr, r1 = r0 + 16;
        const char* px0 = (const char*)((r0 < rows) ? (h_buf + (size_t)sl[m0 + r0] * HID) : zrow) + sxg;
        const char* px1 = (const char*)((r1 < rows) ? (h_buf + (size_t)sl[m0 + r1] * HID) : zrow) + sxg;

        f32x4 acc[4];
#pragma unroll
        for (int ms = 0; ms < 4; ++ms) acc[ms] = (f32x4)(0.f);

#pragma unroll
        for (int st = 0; st < 3; ++st) {
            char* dX = b0 + st * 12288 + (2 * wv) * 1024;
            gload16(px0 + st * 64, dX);
            gload16(px1 + st * 64, dX + 1024);
            gload16(pb + st * 128, b0 + st * 12288 + 8192 + wv * 1024);
        }

#pragma unroll 1
        for (int t = 0; t < 64; ++t) {
            if (t < 62)       asm volatile("s_waitcnt vmcnt(6)" ::: "memory");
            else if (t == 62) asm volatile("s_waitcnt vmcnt(3)" ::: "memory");
            else              asm volatile("s_waitcnt vmcnt(0)" ::: "memory");
            __builtin_amdgcn_s_barrier();

            const char* Hb = b0 + (t & 3) * 12288;
            const char* Bb = Hb + 8192;
            bf16x8 af[4];
#pragma unroll
            for (int ms = 0; ms < 4; ++ms) {
                int row = wm * 64 + ms * 16 + fr;
                int slot = (fq + (row >> 1)) & 3;
                af[ms] = *(const bf16x8*)(Hb + row * 64 + slot * 16);
            }
            int rb = wn * 16 + fr;
            f32x4 wa = *(const f32x4*)(Bb + rb * 128 + ((2 * fq) ^ (fr & 7)) * 16);
            f32x4 wb = *(const f32x4*)(Bb + rb * 128 + ((2 * fq + 1) ^ (fr & 7)) * 16);
            bf16x8 bw = cat8(cvt4(wa), cvt4(wb));
#pragma unroll
            for (int ms = 0; ms < 4; ++ms)
                acc[ms] = __builtin_amdgcn_mfma_f32_16x16x32_bf16(af[ms], bw, acc[ms], 0, 0, 0);

            __builtin_amdgcn_s_barrier();

            if (t < 61) {
                int kt = t + 3, kb = kt & 3;
                char* dX = b0 + kb * 12288 + (2 * wv) * 1024;
                gload16(px0 + kt * 64, dX);
                gload16(px1 + kt * 64, dX + 1024);
                gload16(pb + kt * 128, b0 + kb * 12288 + 8192 + wv * 1024);
            }
        }

#pragma unroll
        for (int ms = 0; ms < 4; ++ms) {
#pragma unroll
            for (int reg = 0; reg < 4; ++reg) {
                int r = wm * 64 + ms * 16 + fq * 4 + reg;
                if (r < rows) {
                    int slot = sl[m0 + r];
                    ybuf[(size_t)slot * DIM + db + wn * 16 + fr] = acc[ms][reg];
                }
            }
        }
    }
}

// ---------------- combine: out[t] = y[2t] + y[2t+1] ----------------
__global__ __launch_bounds__(256) void combine_kernel(const float* __restrict__ ybuf, float* __restrict__ out)
{
    int i = blockIdx.x * 256 + threadIdx.x;
    int t = i >> 8;
    int c = i & 255;
    const float4* ya = (const float4*)(ybuf + (size_t)(2 * t) * DIM) + c;
    const float4* yb = (const float4*)(ybuf + (size_t)(2 * t + 1) * DIM) + c;
    float4 a = *ya, b = *yb, r;
    r.x = a.x + b.x; r.y = a.y + b.y; r.z = a.z + b.z; r.w = a.w + b.w;
    ((float4*)(out + (size_t)t * DIM))[c] = r;
}

extern "C" void kernel_launch(void* const* d_in, const int* in_sizes, int n_in,
                              void* d_out, int out_size, void* d_ws, size_t ws_size,
                              hipStream_t stream) {
    const float* x  = (const float*)d_in[0];
    const float* rw = (const float*)d_in[1];
    const float* wg = (const float*)d_in[2];
    const float* wu = (const float*)d_in[3];
    const float* wd = (const float*)d_in[4];
    float* out = (float*)d_out;

    char* ws = (char*)d_ws;
    int* counts            = (int*)ws;                                   // 256 B
    int* slot_list         = (int*)(ws + 256);                           // 32 KB
    float* w_list          = (float*)(ws + 256 + NEXP * NTOK * 4);       // 32 KB
    __hip_bfloat16* xb     = (__hip_bfloat16*)(ws + 256 + 2 * NEXP * NTOK * 4);       // 2 MB
    __hip_bfloat16* h_buf  = (__hip_bfloat16*)((char*)xb + (size_t)NTOK * DIM * 2);   // 8 MB
    float* ybuf            = (float*)((char*)h_buf + (size_t)NTOK * TOPK * HID * 2);  // 8 MB
    __hip_bfloat16* zrow   = (__hip_bfloat16*)((char*)ybuf + (size_t)NTOK * TOPK * DIM * 4); // 4 KB zeros

    hipMemsetAsync(counts, 0, NEXP * sizeof(int), stream);
    hipMemsetAsync(zrow, 0, HID * sizeof(__hip_bfloat16), stream);
    router_kernel<<<NTOK, 64, 0, stream>>>(x, rw, xb, counts, slot_list, w_list);
    gateup_mfma<<<1024, 256, 0, stream>>>(xb, wg, wu, counts, slot_list, w_list, zrow, h_buf);
    down_mfma<<<512, 256, 0, stream>>>(h_buf, wd, counts, slot_list, zrow, ybuf);
    combine_kernel<<<NTOK * DIM / 4 / 256, 256, 0, stream>>>(ybuf, out);
}